// Round 5
// baseline (2775.468 us; speedup 1.0000x reference)
//
#include <hip/hip_runtime.h>

#define F_IN 128
#define F_OUT 64
#define TILE 8192

// ---- bf16 helpers (manual, RTN) ----
__device__ inline float bf2f(unsigned short u) {
    unsigned int v = ((unsigned int)u) << 16;
    return __builtin_bit_cast(float, v);
}
__device__ inline unsigned short f2bf(float f) {
    unsigned int x = __builtin_bit_cast(unsigned int, f);
    unsigned int r = x + 0x7FFFu + ((x >> 16) & 1u);
    return (unsigned short)(r >> 16);
}

// ---------------- A1: coarse bucket histogram (bucket = col >> 7) ----------------
__global__ void bucket_count(const int* __restrict__ col, int* __restrict__ bcount,
                             int E, int NB) {
    __shared__ int h[1024];
    for (int i = threadIdx.x; i < NB; i += 256) h[i] = 0;
    __syncthreads();
    for (int e = blockIdx.x * 256 + threadIdx.x; e < E; e += gridDim.x * 256)
        atomicAdd(&h[col[e] >> 7], 1);
    __syncthreads();
    for (int i = threadIdx.x; i < NB; i += 256) {
        int v = h[i];
        if (v) atomicAdd(&bcount[i], v);
    }
}

// ---------------- A1b: scan bucket counts (single block, NB <= 1024) ----------------
__global__ void bucket_scan(const int* __restrict__ bcount, int* __restrict__ bbase,
                            int* __restrict__ bcursor, int NB) {
    __shared__ int s[1024];
    const int t = threadIdx.x;
    const int v = (t < NB) ? bcount[t] : 0;
    s[t] = v;
    __syncthreads();
    for (int off = 1; off < 1024; off <<= 1) {
        int tmp = (t >= off) ? s[t - off] : 0;
        __syncthreads();
        s[t] += tmp;
        __syncthreads();
    }
    if (t < NB) {
        bbase[t + 1] = s[t];           // inclusive -> base of next
        bcursor[t * 16] = s[t] - v;    // exclusive base, 64B-strided cursors
    }
    if (t == 0) bbase[0] = 0;
}

// ---------------- A2: tile-privatized fill — each tile reserves private sub-ranges ----------------
__global__ void tile_fill(const int* __restrict__ row, const int* __restrict__ col,
                          int* __restrict__ gcursor, int* __restrict__ bpacked,
                          int E, int NB) {
    __shared__ int hist[1024];
    __shared__ int cur[1024];
    const int base = blockIdx.x * TILE;
    const int n = min(TILE, E - base);
    for (int i = threadIdx.x; i < NB; i += 256) hist[i] = 0;
    __syncthreads();
    for (int i = threadIdx.x; i < n; i += 256)
        atomicAdd(&hist[col[base + i] >> 7], 1);
    __syncthreads();
    for (int b = threadIdx.x; b < NB; b += 256) {
        const int h = hist[b];
        cur[b] = h ? atomicAdd(&gcursor[b * 16], h) : 0;
    }
    __syncthreads();
    for (int i = threadIdx.x; i < n; i += 256) {
        const int c = col[base + i];
        const int b = c >> 7;
        const int pos = atomicAdd(&cur[b], 1);
        bpacked[pos] = row[base + i] | ((c & 127) << 17);
    }
}

// ---------------- B1: per-bucket — deg hist, dinv, seg bounds, node-sorted srcs ----------------
__global__ void build_kernel(const int* __restrict__ bbase, const int* __restrict__ bpacked,
                             int* __restrict__ srcs, float* __restrict__ dinv,
                             int2* __restrict__ segs, int N) {
    const int b = blockIdx.x;
    const int lo = bbase[b], hi = bbase[b + 1];
    __shared__ int hist[128];
    __shared__ int excl[128];
    __shared__ int cursor[128];
    const int t = threadIdx.x;   // 256 threads
    if (t < 128) hist[t] = 0;
    __syncthreads();
    for (int i = lo + t; i < hi; i += 256)
        atomicAdd(&hist[bpacked[i] >> 17], 1);
    __syncthreads();
    if (t < 128) excl[t] = hist[t];
    __syncthreads();
    for (int off = 1; off < 128; off <<= 1) {
        int v = (t < 128 && t >= off) ? excl[t - off] : 0;
        __syncthreads();
        if (t < 128) excl[t] += v;
        __syncthreads();
    }
    if (t < 128) {
        const int ex = excl[t] - hist[t];   // exclusive within bucket
        cursor[t] = ex;
        const int node = b * 128 + t;
        if (node < N) {
            dinv[node] = rsqrtf((float)hist[t] + 1.0f);   // +1 self-loop
            segs[node] = make_int2(lo + ex, hist[t]);
        }
    }
    __syncthreads();
    for (int i = lo + t; i < hi; i += 256) {
        const int p = bpacked[i];
        const int pos = atomicAdd(&cursor[p >> 17], 1);
        srcs[lo + pos] = p & 0x1FFFF;
    }
}

// ---------------- y'[v] = (x[v] @ [Wmu|Wls]) * dinv[v], stored packed bf16 (uint) ----------------
// 128 threads/block = 2 waves; wave w owns nodes 8w..8w+7; lane owns a column PAIR.
// LDS x-tile read as float4 (k-chunks of 4); y stored as uint (2 bf16) coalesced.
__global__ void gemm_kernel(const float* __restrict__ x, const float* __restrict__ Wmu,
                            const float* __restrict__ Wls, const float* __restrict__ dinv,
                            unsigned int* __restrict__ y, int N) {
    __shared__ float xs[16 * F_IN];
    const int tid = threadIdx.x;          // 0..127
    const int wv = tid >> 6;              // wave 0/1
    const int lane = tid & 63;
    const int base = blockIdx.x * 16;
    if (base >= N) return;
    const int nn = min(16, N - base);
    if (nn == 16) {
        const float4* xg = (const float4*)(x + (size_t)base * F_IN);
        float4* xs4 = (float4*)xs;
        for (int idx = tid; idx < 16 * F_IN / 4; idx += 128) xs4[idx] = xg[idx];
    } else {
        for (int idx = tid; idx < nn * F_IN; idx += 128)
            xs[idx] = x[(size_t)base * F_IN + idx];
    }
    __syncthreads();
    // lane < 32 -> Wmu cols (2l, 2l+1); lane >= 32 -> Wls cols (2l-64, 2l-63)
    const float* W0 = (lane < 32) ? Wmu : Wls;
    const int coff = (lane < 32) ? (2 * lane) : (2 * lane - 64);
    const int nbase = wv * 8;
    float acc[8][2];
#pragma unroll
    for (int n = 0; n < 8; n++) { acc[n][0] = 0.f; acc[n][1] = 0.f; }
    for (int k = 0; k < F_IN; k += 4) {
        float4 xv[8];
#pragma unroll
        for (int n = 0; n < 8; n++)
            xv[n] = *(const float4*)&xs[(nbase + n) * F_IN + k];
#pragma unroll
        for (int kk = 0; kk < 4; kk++) {
            const float2 w = *(const float2*)&W0[(size_t)(k + kk) * F_OUT + coff];
#pragma unroll
            for (int n = 0; n < 8; n++) {
                const float xvv = (kk == 0) ? xv[n].x : (kk == 1) ? xv[n].y
                                 : (kk == 2) ? xv[n].z : xv[n].w;
                acc[n][0] = fmaf(xvv, w.x, acc[n][0]);
                acc[n][1] = fmaf(xvv, w.y, acc[n][1]);
            }
        }
    }
#pragma unroll
    for (int n = 0; n < 8; n++) {
        const int node = base + nbase + n;
        if (node < N) {
            const float dv = dinv[node];
            const unsigned lo = f2bf(acc[n][0] * dv);
            const unsigned hi = f2bf(acc[n][1] * dv);
            y[(size_t)node * 64 + lane] = lo | (hi << 16);
        }
    }
}

// ---------------- gather: one WAVE per node; 2 edges per load instruction ----------------
// Lanes 0-31 handle even edges, 32-63 odd edges; each lane reads uint2 = 4 bf16 features.
// One global_load_dwordx2 covers TWO y rows (512 B). 8-edge unroll = 4 loads in flight.
__global__ void gather_kernel(const int2* __restrict__ segs, const int* __restrict__ srcs,
                              const uint2* __restrict__ y4, const float* __restrict__ dinv,
                              const float* __restrict__ bmu, const float* __restrict__ bls,
                              float* __restrict__ out, int N) {
    const int wid = threadIdx.x >> 6;
    const int lane = threadIdx.x & 63;
    const int c = blockIdx.x * 4 + wid;
    if (c >= N) return;
    const int2 sg = segs[c];
    const int start = sg.x, end = sg.x + sg.y;
    const int half = lane >> 5;      // 0 = even edge of pair, 1 = odd
    const int q = lane & 31;         // uint2 index within row (features 4q..4q+3)

    float4 A = make_float4(0.f, 0.f, 0.f, 0.f);
    float4 B = make_float4(0.f, 0.f, 0.f, 0.f);
    float4 C = make_float4(0.f, 0.f, 0.f, 0.f);
    float4 D = make_float4(0.f, 0.f, 0.f, 0.f);

#define ACC4(Aref, u)                                                     \
    do {                                                                  \
        Aref.x += bf2f((unsigned short)(u).x);                            \
        Aref.y += bf2f((unsigned short)((u).x >> 16));                    \
        Aref.z += bf2f((unsigned short)(u).y);                            \
        Aref.w += bf2f((unsigned short)((u).y >> 16));                    \
    } while (0)

    int i = start;
    for (; i + 8 <= end; i += 8) {
        // uniform scalar loads, per-half select
        const int e0 = srcs[i + 0], e1 = srcs[i + 1];
        const int e2 = srcs[i + 2], e3 = srcs[i + 3];
        const int e4 = srcs[i + 4], e5 = srcs[i + 5];
        const int e6 = srcs[i + 6], e7 = srcs[i + 7];
        const int ra = half ? e1 : e0;
        const int rb = half ? e3 : e2;
        const int rc = half ? e5 : e4;
        const int rd = half ? e7 : e6;
        const uint2 ua = y4[(size_t)ra * 32 + q];
        const uint2 ub = y4[(size_t)rb * 32 + q];
        const uint2 uc = y4[(size_t)rc * 32 + q];
        const uint2 ud = y4[(size_t)rd * 32 + q];
        ACC4(A, ua);
        ACC4(B, ub);
        ACC4(C, uc);
        ACC4(D, ud);
    }
    for (; i < end; i += 2) {
        const int j = i + half;
        const bool act = j < end;
        const int r = act ? srcs[j] : srcs[start];   // start < end here, safe addr
        const uint2 u = y4[(size_t)r * 32 + q];
        if (act) ACC4(A, u);
    }
#undef ACC4

    A.x += B.x + C.x + D.x;
    A.y += B.y + C.y + D.y;
    A.z += B.z + C.z + D.z;
    A.w += B.w + C.w + D.w;
    // combine the two halves (edge parity)
    A.x += __shfl_xor(A.x, 32);
    A.y += __shfl_xor(A.y, 32);
    A.z += __shfl_xor(A.z, 32);
    A.w += __shfl_xor(A.w, 32);
    // self-loop
    const uint2 us = y4[(size_t)c * 32 + q];
    A.x += bf2f((unsigned short)us.x);
    A.y += bf2f((unsigned short)(us.x >> 16));
    A.z += bf2f((unsigned short)us.y);
    A.w += bf2f((unsigned short)(us.y >> 16));
    const float dv = dinv[c];
    const int f = q * 4;
    if (lane < 32) {
        if (q < 16) {
            const float4 bm = ((const float4*)bmu)[q];
            float4 r = make_float4(bm.x + A.x * dv, bm.y + A.y * dv,
                                   bm.z + A.z * dv, bm.w + A.w * dv);
            *(float4*)&out[(size_t)c * F_OUT + f] = r;
        } else {
            const float4 bl = ((const float4*)bls)[q - 16];
            float4 r = make_float4(bl.x + A.x * dv, bl.y + A.y * dv,
                                   bl.z + A.z * dv, bl.w + A.w * dv);
            *(float4*)&out[(size_t)N * F_OUT + (size_t)c * F_OUT + (f - F_OUT)] = r;
        }
    }
}

extern "C" void kernel_launch(void* const* d_in, const int* in_sizes, int n_in,
                              void* d_out, int out_size, void* d_ws, size_t ws_size,
                              hipStream_t stream) {
    const float* x   = (const float*)d_in[0];
    const int*   ei  = (const int*)d_in[1];
    const float* Wmu = (const float*)d_in[2];
    const float* bmu = (const float*)d_in[3];
    const float* Wls = (const float*)d_in[4];
    const float* bls = (const float*)d_in[5];
    float* out = (float*)d_out;

    const int N = in_sizes[0] / F_IN;     // 100000
    const int E = in_sizes[1] / 2;        // 3200000
    const int* row = ei;
    const int* col = ei + E;
    const int NB = (N + 127) >> 7;        // 782 buckets of 128 nodes

    // workspace layout (512B aligned):
    char* p = (char*)d_ws;
    auto alloc = [&](size_t bytes) {
        char* r = p;
        p += (bytes + 511) & ~(size_t)511;
        return r;
    };
    int*   bcount  = (int*)  alloc((size_t)NB * 4);
    int*   bbase   = (int*)  alloc((size_t)(NB + 1) * 4);
    int*   bcursor = (int*)  alloc((size_t)NB * 16 * 4);   // 64B-strided cursors
    int*   bpacked = (int*)  alloc((size_t)E * 4);
    int*   srcs    = (int*)  alloc((size_t)E * 4);
    int2*  segs    = (int2*) alloc((size_t)N * 8);
    float* dinv    = (float*)alloc((size_t)N * 4);
    unsigned int* y = (unsigned int*)alloc((size_t)N * F_IN * 2);

    const int ntiles = (E + TILE - 1) / TILE;

    hipMemsetAsync(bcount, 0, (size_t)NB * 4, stream);
    bucket_count<<<512, 256, 0, stream>>>(col, bcount, E, NB);
    bucket_scan<<<1, 1024, 0, stream>>>(bcount, bbase, bcursor, NB);
    tile_fill<<<ntiles, 256, 0, stream>>>(row, col, bcursor, bpacked, E, NB);
    build_kernel<<<NB, 256, 0, stream>>>(bbase, bpacked, srcs, dinv, segs, N);
    gemm_kernel<<<(N + 15) / 16, 128, 0, stream>>>(x, Wmu, Wls, dinv, y, N);
    gather_kernel<<<(N + 3) / 4, 256, 0, stream>>>(segs, srcs, (const uint2*)y,
                                                   dinv, bmu, bls, out, N);
}

// Round 6
// 399.814 us; speedup vs baseline: 6.9419x; 6.9419x over previous
//
#include <hip/hip_runtime.h>

#define F_IN 128
#define F_OUT 64
#define TILE 8192

// ---- bf16 helpers (manual, RTN) ----
__device__ inline float bf2f(unsigned short u) {
    unsigned int v = ((unsigned int)u) << 16;
    return __builtin_bit_cast(float, v);
}
__device__ inline unsigned short f2bf(float f) {
    unsigned int x = __builtin_bit_cast(unsigned int, f);
    unsigned int r = x + 0x7FFFu + ((x >> 16) & 1u);
    return (unsigned short)(r >> 16);
}

// ---------------- A1: coarse bucket histogram (bucket = col >> 7) ----------------
__global__ void bucket_count(const int* __restrict__ col, int* __restrict__ bcount,
                             int E, int NB) {
    __shared__ int h[1024];
    for (int i = threadIdx.x; i < NB; i += 256) h[i] = 0;
    __syncthreads();
    for (int e = blockIdx.x * 256 + threadIdx.x; e < E; e += gridDim.x * 256)
        atomicAdd(&h[col[e] >> 7], 1);
    __syncthreads();
    for (int i = threadIdx.x; i < NB; i += 256) {
        int v = h[i];
        if (v) atomicAdd(&bcount[i], v);
    }
}

// ---------------- A1b: scan bucket counts (single block, NB <= 1024) ----------------
__global__ void bucket_scan(const int* __restrict__ bcount, int* __restrict__ bbase,
                            int* __restrict__ bcursor, int NB) {
    __shared__ int s[1024];
    const int t = threadIdx.x;
    const int v = (t < NB) ? bcount[t] : 0;
    s[t] = v;
    __syncthreads();
    for (int off = 1; off < 1024; off <<= 1) {
        int tmp = (t >= off) ? s[t - off] : 0;
        __syncthreads();
        s[t] += tmp;
        __syncthreads();
    }
    if (t < NB) {
        bbase[t + 1] = s[t];           // inclusive -> base of next
        bcursor[t * 16] = s[t] - v;    // exclusive base, 64B-strided cursors
    }
    if (t == 0) bbase[0] = 0;
}

// ---------------- A2: tile-privatized fill — each tile reserves private sub-ranges ----------------
__global__ void tile_fill(const int* __restrict__ row, const int* __restrict__ col,
                          int* __restrict__ gcursor, int* __restrict__ bpacked,
                          int E, int NB) {
    __shared__ int hist[1024];
    __shared__ int cur[1024];
    const int base = blockIdx.x * TILE;
    const int n = min(TILE, E - base);
    for (int i = threadIdx.x; i < NB; i += 256) hist[i] = 0;
    __syncthreads();
    for (int i = threadIdx.x; i < n; i += 256)
        atomicAdd(&hist[col[base + i] >> 7], 1);
    __syncthreads();
    for (int b = threadIdx.x; b < NB; b += 256) {
        const int h = hist[b];
        cur[b] = h ? atomicAdd(&gcursor[b * 16], h) : 0;
    }
    __syncthreads();
    for (int i = threadIdx.x; i < n; i += 256) {
        const int c = col[base + i];
        const int b = c >> 7;
        const int pos = atomicAdd(&cur[b], 1);
        bpacked[pos] = row[base + i] | ((c & 127) << 17);
    }
}

// ---------------- B1: per-bucket — deg hist, dinv, seg bounds, node-sorted srcs ----------------
__global__ void build_kernel(const int* __restrict__ bbase, const int* __restrict__ bpacked,
                             int* __restrict__ srcs, float* __restrict__ dinv,
                             int2* __restrict__ segs, int N) {
    const int b = blockIdx.x;
    const int lo = bbase[b], hi = bbase[b + 1];
    __shared__ int hist[128];
    __shared__ int excl[128];
    __shared__ int cursor[128];
    const int t = threadIdx.x;   // 256 threads
    if (t < 128) hist[t] = 0;
    __syncthreads();
    for (int i = lo + t; i < hi; i += 256)
        atomicAdd(&hist[bpacked[i] >> 17], 1);
    __syncthreads();
    if (t < 128) excl[t] = hist[t];
    __syncthreads();
    for (int off = 1; off < 128; off <<= 1) {
        int v = (t < 128 && t >= off) ? excl[t - off] : 0;
        __syncthreads();
        if (t < 128) excl[t] += v;
        __syncthreads();
    }
    if (t < 128) {
        const int ex = excl[t] - hist[t];   // exclusive within bucket
        cursor[t] = ex;
        const int node = b * 128 + t;
        if (node < N) {
            dinv[node] = rsqrtf((float)hist[t] + 1.0f);   // +1 self-loop
            segs[node] = make_int2(lo + ex, hist[t]);
        }
    }
    __syncthreads();
    for (int i = lo + t; i < hi; i += 256) {
        const int p = bpacked[i];
        const int pos = atomicAdd(&cursor[p >> 17], 1);
        srcs[lo + pos] = p & 0x1FFFF;
    }
}

// ---------------- y'[v] = (x[v] @ [Wmu|Wls]) * dinv[v], stored packed bf16 (uint) ----------------
// 128 threads/block = 2 waves; wave w owns nodes 8w..8w+7; lane owns a column PAIR.
// Register discipline: hoist 4 W float2s per k-chunk, consume each float4 x-vector
// immediately (single live xv) -> ~45 live VGPRs, no spill. __launch_bounds__(128)
// so the allocator isn't capped at 64 VGPRs (the round-5 spill disaster).
__global__ __launch_bounds__(128) void gemm_kernel(
        const float* __restrict__ x, const float* __restrict__ Wmu,
        const float* __restrict__ Wls, const float* __restrict__ dinv,
        unsigned int* __restrict__ y, int N) {
    __shared__ float xs[16 * F_IN];
    const int tid = threadIdx.x;          // 0..127
    const int wv = tid >> 6;              // wave 0/1
    const int lane = tid & 63;
    const int base = blockIdx.x * 16;
    if (base >= N) return;
    const int nn = min(16, N - base);
    if (nn == 16) {
        const float4* xg = (const float4*)(x + (size_t)base * F_IN);
        float4* xs4 = (float4*)xs;
        for (int idx = tid; idx < 16 * F_IN / 4; idx += 128) xs4[idx] = xg[idx];
    } else {
        for (int idx = tid; idx < nn * F_IN; idx += 128)
            xs[idx] = x[(size_t)base * F_IN + idx];
    }
    __syncthreads();
    // lane < 32 -> Wmu cols (2l, 2l+1); lane >= 32 -> Wls cols (2l-64, 2l-63)
    const float* W0 = (lane < 32) ? Wmu : Wls;
    const int coff = (lane < 32) ? (2 * lane) : (2 * lane - 64);
    const int nbase = wv * 8;
    float acc0[8], acc1[8];
#pragma unroll
    for (int n = 0; n < 8; n++) { acc0[n] = 0.f; acc1[n] = 0.f; }
    for (int k = 0; k < F_IN; k += 4) {
        const float2 w0 = *(const float2*)&W0[(size_t)(k + 0) * F_OUT + coff];
        const float2 w1 = *(const float2*)&W0[(size_t)(k + 1) * F_OUT + coff];
        const float2 w2 = *(const float2*)&W0[(size_t)(k + 2) * F_OUT + coff];
        const float2 w3 = *(const float2*)&W0[(size_t)(k + 3) * F_OUT + coff];
#pragma unroll
        for (int n = 0; n < 8; n++) {
            const float4 xv = *(const float4*)&xs[(nbase + n) * F_IN + k];
            acc0[n] = fmaf(xv.x, w0.x, acc0[n]);
            acc1[n] = fmaf(xv.x, w0.y, acc1[n]);
            acc0[n] = fmaf(xv.y, w1.x, acc0[n]);
            acc1[n] = fmaf(xv.y, w1.y, acc1[n]);
            acc0[n] = fmaf(xv.z, w2.x, acc0[n]);
            acc1[n] = fmaf(xv.z, w2.y, acc1[n]);
            acc0[n] = fmaf(xv.w, w3.x, acc0[n]);
            acc1[n] = fmaf(xv.w, w3.y, acc1[n]);
        }
    }
#pragma unroll
    for (int n = 0; n < 8; n++) {
        const int node = base + nbase + n;
        if (node < N) {
            const float dv = dinv[node];
            const unsigned lo = f2bf(acc0[n] * dv);
            const unsigned hi = f2bf(acc1[n] * dv);
            y[(size_t)node * 64 + lane] = lo | (hi << 16);
        }
    }
}

// ---------------- gather: one WAVE per node; 2 edges per load instruction ----------------
__global__ void gather_kernel(const int2* __restrict__ segs, const int* __restrict__ srcs,
                              const uint2* __restrict__ y4, const float* __restrict__ dinv,
                              const float* __restrict__ bmu, const float* __restrict__ bls,
                              float* __restrict__ out, int N) {
    const int wid = threadIdx.x >> 6;
    const int lane = threadIdx.x & 63;
    const int c = blockIdx.x * 4 + wid;
    if (c >= N) return;
    const int2 sg = segs[c];
    const int start = sg.x, end = sg.x + sg.y;
    const int half = lane >> 5;      // 0 = even edge of pair, 1 = odd
    const int q = lane & 31;         // uint2 index within row (features 4q..4q+3)

    float4 A = make_float4(0.f, 0.f, 0.f, 0.f);
    float4 B = make_float4(0.f, 0.f, 0.f, 0.f);
    float4 C = make_float4(0.f, 0.f, 0.f, 0.f);
    float4 D = make_float4(0.f, 0.f, 0.f, 0.f);

#define ACC4(Aref, u)                                                     \
    do {                                                                  \
        Aref.x += bf2f((unsigned short)(u).x);                            \
        Aref.y += bf2f((unsigned short)((u).x >> 16));                    \
        Aref.z += bf2f((unsigned short)(u).y);                            \
        Aref.w += bf2f((unsigned short)((u).y >> 16));                    \
    } while (0)

    int i = start;
    for (; i + 8 <= end; i += 8) {
        const int e0 = srcs[i + 0], e1 = srcs[i + 1];
        const int e2 = srcs[i + 2], e3 = srcs[i + 3];
        const int e4 = srcs[i + 4], e5 = srcs[i + 5];
        const int e6 = srcs[i + 6], e7 = srcs[i + 7];
        const int ra = half ? e1 : e0;
        const int rb = half ? e3 : e2;
        const int rc = half ? e5 : e4;
        const int rd = half ? e7 : e6;
        const uint2 ua = y4[(size_t)ra * 32 + q];
        const uint2 ub = y4[(size_t)rb * 32 + q];
        const uint2 uc = y4[(size_t)rc * 32 + q];
        const uint2 ud = y4[(size_t)rd * 32 + q];
        ACC4(A, ua);
        ACC4(B, ub);
        ACC4(C, uc);
        ACC4(D, ud);
    }
    for (; i < end; i += 2) {
        const int j = i + half;
        const bool act = j < end;
        const int r = act ? srcs[j] : srcs[start];   // start < end here, safe addr
        const uint2 u = y4[(size_t)r * 32 + q];
        if (act) ACC4(A, u);
    }
#undef ACC4

    A.x += B.x + C.x + D.x;
    A.y += B.y + C.y + D.y;
    A.z += B.z + C.z + D.z;
    A.w += B.w + C.w + D.w;
    // combine the two halves (edge parity)
    A.x += __shfl_xor(A.x, 32);
    A.y += __shfl_xor(A.y, 32);
    A.z += __shfl_xor(A.z, 32);
    A.w += __shfl_xor(A.w, 32);
    // self-loop
    const uint2 us = y4[(size_t)c * 32 + q];
    A.x += bf2f((unsigned short)us.x);
    A.y += bf2f((unsigned short)(us.x >> 16));
    A.z += bf2f((unsigned short)us.y);
    A.w += bf2f((unsigned short)(us.y >> 16));
    const float dv = dinv[c];
    const int f = q * 4;
    if (lane < 32) {
        if (q < 16) {
            const float4 bm = ((const float4*)bmu)[q];
            float4 r = make_float4(bm.x + A.x * dv, bm.y + A.y * dv,
                                   bm.z + A.z * dv, bm.w + A.w * dv);
            *(float4*)&out[(size_t)c * F_OUT + f] = r;
        } else {
            const float4 bl = ((const float4*)bls)[q - 16];
            float4 r = make_float4(bl.x + A.x * dv, bl.y + A.y * dv,
                                   bl.z + A.z * dv, bl.w + A.w * dv);
            *(float4*)&out[(size_t)N * F_OUT + (size_t)c * F_OUT + (f - F_OUT)] = r;
        }
    }
}

extern "C" void kernel_launch(void* const* d_in, const int* in_sizes, int n_in,
                              void* d_out, int out_size, void* d_ws, size_t ws_size,
                              hipStream_t stream) {
    const float* x   = (const float*)d_in[0];
    const int*   ei  = (const int*)d_in[1];
    const float* Wmu = (const float*)d_in[2];
    const float* bmu = (const float*)d_in[3];
    const float* Wls = (const float*)d_in[4];
    const float* bls = (const float*)d_in[5];
    float* out = (float*)d_out;

    const int N = in_sizes[0] / F_IN;     // 100000
    const int E = in_sizes[1] / 2;        // 3200000
    const int* row = ei;
    const int* col = ei + E;
    const int NB = (N + 127) >> 7;        // 782 buckets of 128 nodes

    // workspace layout (512B aligned):
    char* p = (char*)d_ws;
    auto alloc = [&](size_t bytes) {
        char* r = p;
        p += (bytes + 511) & ~(size_t)511;
        return r;
    };
    int*   bcount  = (int*)  alloc((size_t)NB * 4);
    int*   bbase   = (int*)  alloc((size_t)(NB + 1) * 4);
    int*   bcursor = (int*)  alloc((size_t)NB * 16 * 4);   // 64B-strided cursors
    int*   bpacked = (int*)  alloc((size_t)E * 4);
    int*   srcs    = (int*)  alloc((size_t)E * 4);
    int2*  segs    = (int2*) alloc((size_t)N * 8);
    float* dinv    = (float*)alloc((size_t)N * 4);
    unsigned int* y = (unsigned int*)alloc((size_t)N * F_IN * 2);

    const int ntiles = (E + TILE - 1) / TILE;

    hipMemsetAsync(bcount, 0, (size_t)NB * 4, stream);
    bucket_count<<<512, 256, 0, stream>>>(col, bcount, E, NB);
    bucket_scan<<<1, 1024, 0, stream>>>(bcount, bbase, bcursor, NB);
    tile_fill<<<ntiles, 256, 0, stream>>>(row, col, bcursor, bpacked, E, NB);
    build_kernel<<<NB, 256, 0, stream>>>(bbase, bpacked, srcs, dinv, segs, N);
    gemm_kernel<<<(N + 15) / 16, 128, 0, stream>>>(x, Wmu, Wls, dinv, y, N);
    gather_kernel<<<(N + 3) / 4, 256, 0, stream>>>(segs, srcs, (const uint2*)y,
                                                   dinv, bmu, bls, out, N);
}